// Round 3
// baseline (535.265 us; speedup 1.0000x reference)
//
#include <hip/hip_runtime.h>

typedef float   f32x4 __attribute__((ext_vector_type(4)));
typedef _Float16 f16x8 __attribute__((ext_vector_type(8)));

#define DEV static __device__ __forceinline__

// ---- problem constants ----
#define BB 4
#define TT 32
#define DD 768
#define SS 256          // Hp*Wp
#define NHD 12
#define HD 64
#define NSEQ  (BB*SS)   // 1024 sequences
#define MTOK  (NSEQ*TT) // 32768 tokens

DEV void async_copy16(const _Float16* g, _Float16* l) {
  __builtin_amdgcn_global_load_lds(
      (const __attribute__((address_space(1))) unsigned int*)g,
      (__attribute__((address_space(3))) unsigned int*)l,
      16, 0, 0);
}

// XOR-swizzled LDS 16B-chunk index for [rows][4 chunk] tiles (BK=32 f16).
DEV int swz_chunk(int r, int kc) {
  return r * 4 + (kc ^ (r & 3) ^ ((r >> 2) & 3));
}

// ---------------------------------------------------------------------------
// K0a: h (B,T,D,Hp,Wp) fp32 -> A[token][d] f16  (d<->s transpose via LDS)
// ---------------------------------------------------------------------------
__global__ __launch_bounds__(256) void k_transpose_h(const float* __restrict__ h,
                                                     _Float16* __restrict__ A) {
  __shared__ _Float16 Tl[256 * 65];
  const int slab = blockIdx.x;
  const int d0   = blockIdx.y * 64;
  const int t    = threadIdx.x;
  const float4* hv = (const float4*)(h + (slab * DD + d0) * SS);
  #pragma unroll
  for (int i = 0; i < 16; ++i) {
    int dd = i * 4 + (t >> 6);
    int s4 = (t & 63) * 4;
    float4 v = hv[dd * 64 + (t & 63)];
    Tl[(s4 + 0) * 65 + dd] = (_Float16)v.x;
    Tl[(s4 + 1) * 65 + dd] = (_Float16)v.y;
    Tl[(s4 + 2) * 65 + dd] = (_Float16)v.z;
    Tl[(s4 + 3) * 65 + dd] = (_Float16)v.w;
  }
  __syncthreads();
  #pragma unroll
  for (int p = 0; p < 8; ++p) {
    int s  = p * 32 + (t >> 3);
    int dd = (t & 7) * 8;
    f16x8 val;
    #pragma unroll
    for (int j = 0; j < 8; ++j) val[j] = Tl[s * 65 + dd + j];
    *(f16x8*)(A + (slab * SS + s) * DD + d0 + dd) = val;
  }
}

// ---------------------------------------------------------------------------
// K0b: weights fp32 -> f16
// ---------------------------------------------------------------------------
__global__ __launch_bounds__(256) void k_convert_w(const float* __restrict__ Wq,
                                                   const float* __restrict__ Wk,
                                                   const float* __restrict__ Wv,
                                                   const float* __restrict__ Wo,
                                                   _Float16* __restrict__ WQKV,
                                                   _Float16* __restrict__ WoH) {
  int idx = blockIdx.x * 256 + threadIdx.x;
  int row = idx / 96;
  int c8  = (idx % 96) * 8;
  const float* src; _Float16* dst;
  if (row < 768)       { src = Wq + row * 768;          dst = WQKV + row * 768; }
  else if (row < 1536) { src = Wk + (row - 768) * 768;  dst = WQKV + row * 768; }
  else if (row < 2304) { src = Wv + (row - 1536) * 768; dst = WQKV + row * 768; }
  else                 { src = Wo + (row - 2304) * 768; dst = WoH  + (row - 2304) * 768; }
  float4 v0 = *(const float4*)(src + c8);
  float4 v1 = *(const float4*)(src + c8 + 4);
  f16x8 o;
  o[0]=(_Float16)v0.x; o[1]=(_Float16)v0.y; o[2]=(_Float16)v0.z; o[3]=(_Float16)v0.w;
  o[4]=(_Float16)v1.x; o[5]=(_Float16)v1.y; o[6]=(_Float16)v1.z; o[7]=(_Float16)v1.w;
  *(f16x8*)(dst + c8) = o;
}

// ---------------------------------------------------------------------------
// K1: u_pen[(b*256+s)*32 + t] = lam * mean_d u
// ---------------------------------------------------------------------------
__global__ __launch_bounds__(256) void k_upen(const float* __restrict__ u,
                                              const float* __restrict__ lam,
                                              float* __restrict__ upen) {
  int slab = blockIdx.x >> 2;
  int q    = blockIdx.x & 3;
  int s    = threadIdx.x;
  const float* base = u + (slab * DD + q * 192) * SS + s;
  float sum = 0.f;
  for (int d = 0; d < 192; ++d) sum += base[d * SS];
  int b = slab >> 5, tt = slab & 31;
  float l = lam[slab * SS + s];
  atomicAdd(&upen[(b * SS + s) * TT + tt], sum * l * (1.0f / 768.0f));
}

// ---------------------------------------------------------------------------
// K2 v5: QKV GEMM, 256x256 tile, BK=32, 512 thr = 8 waves (2M x 4N).
// TRUE T4 pipeline: quad-buffered LDS (4 K-tiles resident, 128KB), staging
// runs 3 K-tiles ahead, counted s_waitcnt vmcnt(8) in the main loop (NEVER
// drains to 0; tail steps 8->4->0).  Per K-step:
//   { 12x ds_read_b128 (tile t) ; stage tile t+3 (4 gload_lds/thread) ;
//     s_barrier ; lgkmcnt(0)+sched_barrier ; setprio(1) ; 32 MFMA ;
//     setprio(0) ; vmcnt(8) ; s_barrier }
// vmcnt(8) leaves tiles t+2,t+3 in flight, retires t+1 (issued 3 K-steps =
// ~1200cyc earlier > 900cyc HBM latency). barrier#2 publishes t+1 to all
// waves. WAR on buffer reuse safe: per-wave lgkmcnt(0) precedes MFMA and
// barrier#2 precedes the overwriting stage by a full iteration.
// XOR swizzle both-sides (pre-swizzled source / swizzled ds_read): 0 bank
// conflicts (verified R2).
// Epilogue writes packed Qp/Kp/Vp[seq][head][t][hd], Q scaled by 1/8.
// Grid: XCD-chunked swizzle, 9 nt-variants of same mt adjacent (A L2 reuse).
// ---------------------------------------------------------------------------
#define KSTEP(IT, VM, DO_STG)                                                  \
  {                                                                            \
    const int bt_ = (IT) & 3;                                                  \
    const _Float16* Ac = &As[bt_][0];                                          \
    const _Float16* Bc = &Bs[bt_][0];                                          \
    f16x8 af[8], bf[4];                                                        \
    _Pragma("unroll")                                                          \
    for (int mi = 0; mi < 8; ++mi) {                                           \
      int row = wm * 128 + mi * 16 + (lane & 15);                              \
      af[mi] = *(const f16x8*)&Ac[(row * 4 + ((lane >> 4) ^ (row & 3))) * 8];  \
    }                                                                          \
    _Pragma("unroll")                                                          \
    for (int ni = 0; ni < 4; ++ni) {                                           \
      int row = wn * 64 + ni * 16 + (lane & 15);                               \
      bf[ni] = *(const f16x8*)&Bc[(row * 4 + ((lane >> 4) ^ (row & 3))) * 8];  \
    }                                                                          \
    if (DO_STG) {                                                              \
      const int kn_ = ((IT) + 3) * 32;                                         \
      stage(A, m0, &As[((IT) + 3) & 3][0], kn_);                               \
      stage(Bw, n0, &Bs[((IT) + 3) & 3][0], kn_);                              \
    }                                                                          \
    __builtin_amdgcn_s_barrier();                                              \
    asm volatile("s_waitcnt lgkmcnt(0)" ::: "memory");                         \
    __builtin_amdgcn_sched_barrier(0);                                         \
    __builtin_amdgcn_s_setprio(1);                                             \
    _Pragma("unroll")                                                          \
    for (int mi = 0; mi < 8; ++mi)                                             \
      _Pragma("unroll")                                                        \
      for (int ni = 0; ni < 4; ++ni)                                           \
        acc[mi][ni] = __builtin_amdgcn_mfma_f32_16x16x32_f16(af[mi], bf[ni],   \
                                                             acc[mi][ni], 0, 0, 0); \
    __builtin_amdgcn_s_setprio(0);                                             \
    asm volatile("s_waitcnt " VM ::: "memory");                                \
    __builtin_amdgcn_sched_barrier(0);                                         \
    __builtin_amdgcn_s_barrier();                                              \
  }

__global__ __launch_bounds__(512, 2) void k_gemm_qkv(const _Float16* __restrict__ A,
                                                     const _Float16* __restrict__ Bw,
                                                     const float* __restrict__ bq,
                                                     const float* __restrict__ bk,
                                                     const float* __restrict__ bv,
                                                     _Float16* __restrict__ Qp,
                                                     _Float16* __restrict__ Kp,
                                                     _Float16* __restrict__ Vp) {
  __shared__ __align__(16) _Float16 As[4][256 * 32];   // 16KB per buf
  __shared__ __align__(16) _Float16 Bs[4][256 * 32];   // 16KB per buf
  const int swz = (blockIdx.x & 7) * 144 + (blockIdx.x >> 3);   // 1152 = 8*144
  const int mt = swz / 9, nt = swz - mt * 9;
  const int m0 = mt * 256, n0 = nt * 256;
  const int tid = threadIdx.x, lane = tid & 63, w = tid >> 6;
  const int wm = w >> 2, wn = w & 3;       // wave rows wm*128.., cols wn*64..
  f32x4 acc[8][4] = {};

  // stage one matrix's 256x32 K-tile: 1024 16B-chunks, 2 per thread.
  auto stage = [&](const _Float16* __restrict__ g, int grow0, _Float16* l, int k0) {
    #pragma unroll
    for (int li = 0; li < 2; ++li) {
      int cc = tid + 512 * li;             // 16B chunk id, lane-linear dest
      int row = cc >> 2;                   // 4 chunks per 32-f16 row
      int kc = (cc & 3) ^ (row & 3);       // inverse swizzle on SOURCE
      async_copy16(g + (grow0 + row) * DD + k0 + kc * 8, l + cc * 8);
    }
  };

  // prologue: stage tiles 0,1,2 (12 loads/thread); wait tile0 (leave 8).
  stage(A, m0, &As[0][0], 0);  stage(Bw, n0, &Bs[0][0], 0);
  stage(A, m0, &As[1][0], 32); stage(Bw, n0, &Bs[1][0], 32);
  stage(A, m0, &As[2][0], 64); stage(Bw, n0, &Bs[2][0], 64);
  asm volatile("s_waitcnt vmcnt(8)" ::: "memory");
  __builtin_amdgcn_sched_barrier(0);
  __builtin_amdgcn_s_barrier();

  for (int it = 0; it < 21; ++it) KSTEP(it, "vmcnt(8)", 1);
  KSTEP(21, "vmcnt(4)", 0);
  KSTEP(22, "vmcnt(0)", 0);
  KSTEP(23, "vmcnt(0)", 0);

  // epilogue: n -> (sel, head, hd); m -> (b, t, s); packed [seq][head][t][hd]
  const int sel = nt / 3;                                   // 0=Q 1=K 2=V
  const float scale = (sel == 0) ? 0.125f : 1.0f;           // fold 1/sqrt(64)
  const float* bias = (sel == 0) ? bq : ((sel == 1) ? bk : bv);
  _Float16* dst = (sel == 0) ? Qp : ((sel == 1) ? Kp : Vp);
  const int b = mt >> 5, t = mt & 31;
  #pragma unroll
  for (int ni = 0; ni < 4; ++ni) {
    int n768 = nt * 256 - sel * 768 + wn * 64 + ni * 16 + (lane & 15);
    int head = n768 >> 6, hd = n768 & 63;
    float bs = bias[n768];
    long hb = (long)head * 2048 + t * 64 + hd;
    #pragma unroll
    for (int mi = 0; mi < 8; ++mi) {
      f32x4 v = acc[mi][ni];
      #pragma unroll
      for (int r = 0; r < 4; ++r) {
        int s = wm * 128 + mi * 16 + (lane >> 4) * 4 + r;
        long seq = (long)b * 256 + s;
        dst[seq * 24576 + hb] = (_Float16)((v[r] + bs) * scale);
      }
    }
  }
}

// ---------------------------------------------------------------------------
// K3: attention v2. 1 wave per (seq, head); all global reads dense 4KB blocks.
// V transposed through per-wave LDS (stride 66: both sides 2-way = free).
// O written token-major into Abuf for the output GEMM.
// ---------------------------------------------------------------------------
__global__ __launch_bounds__(256) void k_attn(const _Float16* __restrict__ Qp,
                                              const _Float16* __restrict__ Kp,
                                              const _Float16* __restrict__ Vp,
                                              const float* __restrict__ upen,
                                              _Float16* __restrict__ O) {
  __shared__ _Float16 lds[4][32 * 66 + 32 * 40];   // per-wave: Vs[32][66], Ps[32][40]
  const int w = threadIdx.x >> 6, lane = threadIdx.x & 63;
  const int seq = blockIdx.x / 3, hg = blockIdx.x % 3;
  const int head = hg * 4 + w;
  const int b = seq >> 8, s = seq & 255;
  _Float16* Vs = &lds[w][0];
  _Float16* Ps = &lds[w][32 * 66];
  const long base = (long)(seq * NHD + head) * 2048;
  const _Float16* Qb = Qp + base;
  const _Float16* Kb = Kp + base;
  const _Float16* Vb = Vp + base;

  // stage V (dense 4KB) -> LDS stride 66, f16x2 writes (2-way, free)
  {
    int t = lane & 31, hh = (lane >> 5) * 32;
    f16x8 vc[4];
    #pragma unroll
    for (int c = 0; c < 4; ++c) vc[c] = *(const f16x8*)(Vb + t * 64 + hh + c * 8);
    #pragma unroll
    for (int c = 0; c < 4; ++c)
      #pragma unroll
      for (int p = 0; p < 4; ++p) {
        union { _Float16 h[2]; unsigned u; } pk;
        pk.h[0] = vc[c][2 * p]; pk.h[1] = vc[c][2 * p + 1];
        *(unsigned*)&Vs[t * 66 + hh + c * 8 + 2 * p] = pk.u;
      }
  }
  // Q/K fragments direct from global (dense within the 4KB block)
  f16x8 qf[2][2], kf[2][2];
  #pragma unroll
  for (int i = 0; i < 2; ++i)
    #pragma unroll
    for (int ks = 0; ks < 2; ++ks) {
      int off = (i * 16 + (lane & 15)) * 64 + ks * 32 + (lane >> 4) * 8;
      qf[i][ks] = *(const f16x8*)(Qb + off);
      kf[i][ks] = *(const f16x8*)(Kb + off);
    }
  // scores = (Q/8) . K^T
  f32x4 sc[2][2] = {};
  #pragma unroll
  for (int mq = 0; mq < 2; ++mq)
    #pragma unroll
    for (int nk = 0; nk < 2; ++nk)
      #pragma unroll
      for (int ks = 0; ks < 2; ++ks)
        sc[mq][nk] = __builtin_amdgcn_mfma_f32_16x16x32_f16(qf[mq][ks], kf[nk][ks], sc[mq][nk], 0, 0, 0);

  const float up0 = upen[seq * TT + (lane & 15)];
  const float up1 = upen[seq * TT + 16 + (lane & 15)];

  // softmax over 32 keys per query row
  #pragma unroll
  for (int mq = 0; mq < 2; ++mq) {
    #pragma unroll
    for (int r = 0; r < 4; ++r) {
      float s0 = sc[mq][0][r] - up0;
      float s1 = sc[mq][1][r] - up1;
      float mx = fmaxf(s0, s1);
      #pragma unroll
      for (int off = 1; off < 16; off <<= 1) mx = fmaxf(mx, __shfl_xor(mx, off, 64));
      float e0 = __expf(s0 - mx), e1 = __expf(s1 - mx);
      float sum = e0 + e1;
      #pragma unroll
      for (int off = 1; off < 16; off <<= 1) sum += __shfl_xor(sum, off, 64);
      float inv = 1.0f / sum;
      int row = mq * 16 + (lane >> 4) * 4 + r;
      Ps[row * 40 + (lane & 15)]      = (_Float16)(e0 * inv);
      Ps[row * 40 + 16 + (lane & 15)] = (_Float16)(e1 * inv);
    }
  }
  // PV
  f16x8 pf[2];
  #pragma unroll
  for (int mq = 0; mq < 2; ++mq)
    pf[mq] = *(const f16x8*)(Ps + (mq * 16 + (lane & 15)) * 40 + (lane >> 4) * 8);
  f32x4 oacc[2][4] = {};
  #pragma unroll
  for (int nh = 0; nh < 4; ++nh) {
    int hd = nh * 16 + (lane & 15);
    f16x8 vf;
    #pragma unroll
    for (int j = 0; j < 8; ++j) vf[j] = Vs[((lane >> 4) * 8 + j) * 66 + hd];  // 2-way, free
    #pragma unroll
    for (int mq = 0; mq < 2; ++mq)
      oacc[mq][nh] = __builtin_amdgcn_mfma_f32_16x16x32_f16(pf[mq], vf, oacc[mq][nh], 0, 0, 0);
  }
  // write O token-major [m][768]
  #pragma unroll
  for (int mq = 0; mq < 2; ++mq)
    #pragma unroll
    for (int nh = 0; nh < 4; ++nh) {
      int hd = nh * 16 + (lane & 15);
      #pragma unroll
      for (int r = 0; r < 4; ++r) {
        int t = mq * 16 + (lane >> 4) * 4 + r;
        O[((long)((b << 5) + t) * SS + s) * DD + head * HD + hd] = (_Float16)oacc[mq][nh][r];
      }
    }
}

// ---------------------------------------------------------------------------
// K4: output GEMM, swapped operands: C'[R][token] = Wo[R][:] . O[token][:]
// Block tile 128R x 256tok, 4 waves of 64x128. ct-fastest for XCD locality.
// Writes final (B,T,D,Hp,Wp) fp32 with s-contiguous coalesced stores.
// ---------------------------------------------------------------------------
__global__ __launch_bounds__(256, 2) void k_gemm_out(const _Float16* __restrict__ Wn,
                                                     const _Float16* __restrict__ O,
                                                     const float* __restrict__ bo,
                                                     float* __restrict__ out) {
  __shared__ _Float16 As[128 * 32];   // Wo rows
  __shared__ _Float16 Bs[256 * 32];   // O token rows
  const int ct = blockIdx.x & 127, rt = blockIdx.x >> 7;   // ct-fastest
  const int R0 = rt * 128, C0 = ct * 256;
  const int tid = threadIdx.x, w = tid >> 6, lane = tid & 63;
  const int wr = (w >> 1) * 64, wcc = (w & 1) * 128;
  f32x4 acc[4][8] = {};
  for (int it = 0; it < 24; ++it) {
    const int k0 = it * 32;
    __syncthreads();
    #pragma unroll
    for (int i = 0; i < 2; ++i) {
      int c = tid + 256 * i;
      int row = c >> 2;
      int coff = ((c & 3) ^ (row & 3) ^ ((row >> 2) & 3)) * 8;
      _Float16* ldsA = (_Float16*)((char*)As + (w * 1024 + i * 4096 + lane * 16));
      async_copy16(Wn + (R0 + row) * DD + k0 + coff, ldsA);
    }
    #pragma unroll
    for (int i = 0; i < 4; ++i) {
      int c = tid + 256 * i;
      int row = c >> 2;
      int coff = ((c & 3) ^ (row & 3) ^ ((row >> 2) & 3)) * 8;
      _Float16* ldsB = (_Float16*)((char*)Bs + (w * 1024 + i * 4096 + lane * 16));
      async_copy16(O + (C0 + row) * DD + k0 + coff, ldsB);
    }
    __syncthreads();
    f16x8 af[4], bf[8];
    #pragma unroll
    for (int ri = 0; ri < 4; ++ri)
      af[ri] = *(const f16x8*)&As[swz_chunk(wr + ri * 16 + (lane & 15), lane >> 4) * 8];
    #pragma unroll
    for (int ci = 0; ci < 8; ++ci)
      bf[ci] = *(const f16x8*)&Bs[swz_chunk(wcc + ci * 16 + (lane & 15), lane >> 4) * 8];
    #pragma unroll
    for (int ri = 0; ri < 4; ++ri)
      #pragma unroll
      for (int ci = 0; ci < 8; ++ci)
        acc[ri][ci] = __builtin_amdgcn_mfma_f32_16x16x32_f16(af[ri], bf[ci], acc[ri][ci], 0, 0, 0);
  }
  const int slab = ct;                 // C-tile = all 256 tokens of one slab
  #pragma unroll
  for (int ri = 0; ri < 4; ++ri) {
    #pragma unroll
    for (int ci = 0; ci < 8; ++ci) {
      int s = wcc + ci * 16 + (lane & 15);
      f32x4 v = acc[ri][ci];
      #pragma unroll
      for (int r = 0; r < 4; ++r) {
        int R = R0 + wr + ri * 16 + (lane >> 4) * 4 + r;
        out[((long)slab * DD + R) * SS + s] = v[r] + bo[R];
      }
    }
  }
}

// ---------------------------------------------------------------------------
// host launcher.  ws layout (~197 MiB):
//   [0)          A f16 [32768][768]  (reused as O after attention)
//   [50331648)   WQKV f16 [2304][768]
//   [53870592)   Wo   f16 [768][768]
//   [55050240)   upen f32 [32768]
//   [55181312)   Qp f16 [1024][12][32][64]
//   [105512960)  Kp f16  (same shape)
//   [155844608)  Vp f16  (same shape)   end 206176256
// ---------------------------------------------------------------------------
extern "C" void kernel_launch(void* const* d_in, const int* in_sizes, int n_in,
                              void* d_out, int out_size, void* d_ws, size_t ws_size,
                              hipStream_t stream) {
  const float* h   = (const float*)d_in[0];
  const float* u   = (const float*)d_in[1];
  const float* lam = (const float*)d_in[2];
  const float* Wq  = (const float*)d_in[3];
  const float* bq  = (const float*)d_in[4];
  const float* Wk  = (const float*)d_in[5];
  const float* bk  = (const float*)d_in[6];
  const float* Wv  = (const float*)d_in[7];
  const float* bv  = (const float*)d_in[8];
  const float* Wo  = (const float*)d_in[9];
  const float* bo  = (const float*)d_in[10];
  float* out = (float*)d_out;

  char* ws = (char*)d_ws;
  _Float16* Abuf = (_Float16*)(ws);
  _Float16* WQKV = (_Float16*)(ws + 50331648);
  _Float16* WoH  = (_Float16*)(ws + 53870592);
  float*    upen = (float*)   (ws + 55050240);
  _Float16* Qp   = (_Float16*)(ws + 55181312);
  _Float16* Kp   = (_Float16*)(ws + 105512960);
  _Float16* Vp   = (_Float16*)(ws + 155844608);

  hipMemsetAsync(upen, 0, 32768 * sizeof(float), stream);
  k_transpose_h<<<dim3(128, 12), 256, 0, stream>>>(h, Abuf);
  k_convert_w<<<1152, 256, 0, stream>>>(Wq, Wk, Wv, Wo, WQKV, WoH);
  k_upen<<<512, 256, 0, stream>>>(u, lam, upen);
  k_gemm_qkv<<<1152, 512, 0, stream>>>(Abuf, WQKV, bq, bk, bv, Qp, Kp, Vp);
  k_attn<<<1024 * 3, 256, 0, stream>>>(Qp, Kp, Vp, upen, Abuf);
  k_gemm_out<<<128 * 6, 256, 0, stream>>>(WoH, Abuf, bo, out);
}

// Round 4
// 524.473 us; speedup vs baseline: 1.0206x; 1.0206x over previous
//
#include <hip/hip_runtime.h>

typedef float   f32x4 __attribute__((ext_vector_type(4)));
typedef _Float16 f16x8 __attribute__((ext_vector_type(8)));
typedef _Float16 f16x4 __attribute__((ext_vector_type(4)));

#define DEV static __device__ __forceinline__

// ---- problem constants ----
#define BB 4
#define TT 32
#define DD 768
#define SS 256          // Hp*Wp
#define NHD 12
#define HD 64
#define NSEQ  (BB*SS)   // 1024 sequences
#define MTOK  (NSEQ*TT) // 32768 tokens

DEV void async_copy16(const _Float16* g, _Float16* l) {
  __builtin_amdgcn_global_load_lds(
      (const __attribute__((address_space(1))) unsigned int*)g,
      (__attribute__((address_space(3))) unsigned int*)l,
      16, 0, 0);
}

// XOR-swizzled LDS 16B-chunk index for [rows][4 chunk] tiles (BK=32 f16).
DEV int swz_chunk(int r, int kc) {
  return r * 4 + (kc ^ (r & 3) ^ ((r >> 2) & 3));
}

// ---------------------------------------------------------------------------
// K0a: h (B,T,D,Hp,Wp) fp32 -> A[token][d] f16  (d<->s transpose via LDS)
// ---------------------------------------------------------------------------
__global__ __launch_bounds__(256) void k_transpose_h(const float* __restrict__ h,
                                                     _Float16* __restrict__ A) {
  __shared__ _Float16 Tl[256 * 65];
  const int slab = blockIdx.x;
  const int d0   = blockIdx.y * 64;
  const int t    = threadIdx.x;
  const float4* hv = (const float4*)(h + (slab * DD + d0) * SS);
  #pragma unroll
  for (int i = 0; i < 16; ++i) {
    int dd = i * 4 + (t >> 6);
    int s4 = (t & 63) * 4;
    float4 v = hv[dd * 64 + (t & 63)];
    Tl[(s4 + 0) * 65 + dd] = (_Float16)v.x;
    Tl[(s4 + 1) * 65 + dd] = (_Float16)v.y;
    Tl[(s4 + 2) * 65 + dd] = (_Float16)v.z;
    Tl[(s4 + 3) * 65 + dd] = (_Float16)v.w;
  }
  __syncthreads();
  #pragma unroll
  for (int p = 0; p < 8; ++p) {
    int s  = p * 32 + (t >> 3);
    int dd = (t & 7) * 8;
    f16x8 val;
    #pragma unroll
    for (int j = 0; j < 8; ++j) val[j] = Tl[s * 65 + dd + j];
    *(f16x8*)(A + (slab * SS + s) * DD + d0 + dd) = val;
  }
}

// ---------------------------------------------------------------------------
// K0b: weights fp32 -> f16
// ---------------------------------------------------------------------------
__global__ __launch_bounds__(256) void k_convert_w(const float* __restrict__ Wq,
                                                   const float* __restrict__ Wk,
                                                   const float* __restrict__ Wv,
                                                   const float* __restrict__ Wo,
                                                   _Float16* __restrict__ WQKV,
                                                   _Float16* __restrict__ WoH) {
  int idx = blockIdx.x * 256 + threadIdx.x;
  int row = idx / 96;
  int c8  = (idx % 96) * 8;
  const float* src; _Float16* dst;
  if (row < 768)       { src = Wq + row * 768;          dst = WQKV + row * 768; }
  else if (row < 1536) { src = Wk + (row - 768) * 768;  dst = WQKV + row * 768; }
  else if (row < 2304) { src = Wv + (row - 1536) * 768; dst = WQKV + row * 768; }
  else                 { src = Wo + (row - 2304) * 768; dst = WoH  + (row - 2304) * 768; }
  float4 v0 = *(const float4*)(src + c8);
  float4 v1 = *(const float4*)(src + c8 + 4);
  f16x8 o;
  o[0]=(_Float16)v0.x; o[1]=(_Float16)v0.y; o[2]=(_Float16)v0.z; o[3]=(_Float16)v0.w;
  o[4]=(_Float16)v1.x; o[5]=(_Float16)v1.y; o[6]=(_Float16)v1.z; o[7]=(_Float16)v1.w;
  *(f16x8*)(dst + c8) = o;
}

// ---------------------------------------------------------------------------
// K1: u_pen[(b*256+s)*32 + t] = lam * mean_d u
// ---------------------------------------------------------------------------
__global__ __launch_bounds__(256) void k_upen(const float* __restrict__ u,
                                              const float* __restrict__ lam,
                                              float* __restrict__ upen) {
  int slab = blockIdx.x >> 2;
  int q    = blockIdx.x & 3;
  int s    = threadIdx.x;
  const float* base = u + (slab * DD + q * 192) * SS + s;
  float sum = 0.f;
  for (int d = 0; d < 192; ++d) sum += base[d * SS];
  int b = slab >> 5, tt = slab & 31;
  float l = lam[slab * SS + s];
  atomicAdd(&upen[(b * SS + s) * TT + tt], sum * l * (1.0f / 768.0f));
}

// ---------------------------------------------------------------------------
// K2 v6: QKV GEMM, 256x256 tile, BK=32, 512 thr = 8 waves (2M x 4N).
// K-loop IDENTICAL to v5 (ring-4 LDS, depth-3 prefetch, counted vmcnt(8))
// EXCEPT mfma operand order swapped: acc = mfma(bf, af, acc) so D-col =
// lane&15 = s and D-reg = n.  This makes each thread's 4 acc elements
// 4 CONSECUTIVE n -> coalescible epilogue.
// Epilogue v2: bias+scale per-element, pack f16x4 -> LDS Ct[256][264]
// (packed b64 writes, minimum bank passes), barrier, then 16 f16x8
// fully-coalesced global stores per thread (128B-contiguous runs).
// Replaces 128 scattered 2B stores/thread that caused L2/HBM RMW fills
// (FETCH 101MB vs 51MB of inputs).
// ---------------------------------------------------------------------------
#define KSTEP(IT, VM, DO_STG)                                                  \
  {                                                                            \
    const int bt_ = (IT) & 3;                                                  \
    const _Float16* Ac = &sh.g.As[bt_][0];                                     \
    const _Float16* Bc = &sh.g.Bs[bt_][0];                                     \
    f16x8 af[8], bf[4];                                                        \
    _Pragma("unroll")                                                          \
    for (int mi = 0; mi < 8; ++mi) {                                           \
      int row = wm * 128 + mi * 16 + (lane & 15);                              \
      af[mi] = *(const f16x8*)&Ac[(row * 4 + ((lane >> 4) ^ (row & 3))) * 8];  \
    }                                                                          \
    _Pragma("unroll")                                                          \
    for (int ni = 0; ni < 4; ++ni) {                                           \
      int row = wn * 64 + ni * 16 + (lane & 15);                               \
      bf[ni] = *(const f16x8*)&Bc[(row * 4 + ((lane >> 4) ^ (row & 3))) * 8];  \
    }                                                                          \
    if (DO_STG) {                                                              \
      const int kn_ = ((IT) + 3) * 32;                                         \
      stage(A, m0, &sh.g.As[((IT) + 3) & 3][0], kn_);                          \
      stage(Bw, n0, &sh.g.Bs[((IT) + 3) & 3][0], kn_);                         \
    }                                                                          \
    __builtin_amdgcn_s_barrier();                                              \
    asm volatile("s_waitcnt lgkmcnt(0)" ::: "memory");                         \
    __builtin_amdgcn_sched_barrier(0);                                         \
    __builtin_amdgcn_s_setprio(1);                                             \
    _Pragma("unroll")                                                          \
    for (int mi = 0; mi < 8; ++mi)                                             \
      _Pragma("unroll")                                                        \
      for (int ni = 0; ni < 4; ++ni)                                           \
        acc[mi][ni] = __builtin_amdgcn_mfma_f32_16x16x32_f16(bf[ni], af[mi],   \
                                                             acc[mi][ni], 0, 0, 0); \
    __builtin_amdgcn_s_setprio(0);                                             \
    asm volatile("s_waitcnt " VM ::: "memory");                                \
    __builtin_amdgcn_sched_barrier(0);                                         \
    __builtin_amdgcn_s_barrier();                                              \
  }

__global__ __launch_bounds__(512, 2) void k_gemm_qkv(const _Float16* __restrict__ A,
                                                     const _Float16* __restrict__ Bw,
                                                     const float* __restrict__ bq,
                                                     const float* __restrict__ bk,
                                                     const float* __restrict__ bv,
                                                     _Float16* __restrict__ Qp,
                                                     _Float16* __restrict__ Kp,
                                                     _Float16* __restrict__ Vp) {
  __shared__ __align__(16) union ShMem {
    struct { _Float16 As[4][256 * 32]; _Float16 Bs[4][256 * 32]; } g;  // 128KB
    _Float16 Ct[256 * 264];                                            // 135KB
  } sh;
  const int swz = (blockIdx.x & 7) * 144 + (blockIdx.x >> 3);   // 1152 = 8*144
  const int mt = swz / 9, nt = swz - mt * 9;
  const int m0 = mt * 256, n0 = nt * 256;
  const int tid = threadIdx.x, lane = tid & 63, w = tid >> 6;
  const int wm = w >> 2, wn = w & 3;       // wave rows wm*128.., cols wn*64..
  f32x4 acc[8][4] = {};

  // stage one matrix's 256x32 K-tile: 1024 16B-chunks, 2 per thread.
  auto stage = [&](const _Float16* __restrict__ g, int grow0, _Float16* l, int k0) {
    #pragma unroll
    for (int li = 0; li < 2; ++li) {
      int cc = tid + 512 * li;             // 16B chunk id, lane-linear dest
      int row = cc >> 2;                   // 4 chunks per 32-f16 row
      int kc = (cc & 3) ^ (row & 3);       // inverse swizzle on SOURCE
      async_copy16(g + (grow0 + row) * DD + k0 + kc * 8, l + cc * 8);
    }
  };

  // prologue: stage tiles 0,1,2 (12 loads/thread); wait tile0 (leave 8).
  stage(A, m0, &sh.g.As[0][0], 0);  stage(Bw, n0, &sh.g.Bs[0][0], 0);
  stage(A, m0, &sh.g.As[1][0], 32); stage(Bw, n0, &sh.g.Bs[1][0], 32);
  stage(A, m0, &sh.g.As[2][0], 64); stage(Bw, n0, &sh.g.Bs[2][0], 64);
  asm volatile("s_waitcnt vmcnt(8)" ::: "memory");
  __builtin_amdgcn_sched_barrier(0);
  __builtin_amdgcn_s_barrier();

  for (int it = 0; it < 21; ++it) KSTEP(it, "vmcnt(8)", 1);
  KSTEP(21, "vmcnt(4)", 0);
  KSTEP(22, "vmcnt(0)", 0);
  KSTEP(23, "vmcnt(0)", 0);

  // ---- epilogue v2 ----
  // swapped-operand layout: s = wm*128 + mi*16 + (lane&15);
  //                         n = wn*64 + ni*16 + (lane>>4)*4 + r  (r consec!)
  const int sel = nt / 3;                                   // 0=Q 1=K 2=V
  const float scale = (sel == 0) ? 0.125f : 1.0f;           // fold 1/sqrt(64)
  const float* bias = (sel == 0) ? bq : ((sel == 1) ? bk : bv);
  _Float16* dst = (sel == 0) ? Qp : ((sel == 1) ? Kp : Vp);
  const int b = mt >> 5, t = mt & 31;
  const int nbias0 = nt * 256 - sel * 768;                  // sel-local col base

  #pragma unroll
  for (int ni = 0; ni < 4; ++ni) {
    int n_l = wn * 64 + ni * 16 + (lane >> 4) * 4;          // 4-aligned
    float4 bsv = *(const float4*)&bias[nbias0 + n_l];
    #pragma unroll
    for (int mi = 0; mi < 8; ++mi) {
      int s = wm * 128 + mi * 16 + (lane & 15);
      f32x4 v = acc[mi][ni];
      f16x4 pk;
      pk[0] = (_Float16)((v[0] + bsv.x) * scale);
      pk[1] = (_Float16)((v[1] + bsv.y) * scale);
      pk[2] = (_Float16)((v[2] + bsv.z) * scale);
      pk[3] = (_Float16)((v[3] + bsv.w) * scale);
      *(f16x4*)&sh.Ct[s * 264 + n_l] = pk;
    }
  }
  __syncthreads();
  // coalesced stores: thread -> (s, n-octet); 8 lanes = 128B contiguous run.
  const long sbase = ((long)b * 256) * 24576 + (long)t * 64;
  #pragma unroll
  for (int rep = 0; rep < 16; ++rep) {
    int id = rep * 512 + tid;           // 8192 octets = 256s x 32
    int s = id >> 5, c8 = id & 31;
    int n = c8 * 8;
    f16x8 v = *(const f16x8*)&sh.Ct[s * 264 + n];
    int n768 = nbias0 + n;
    int head = n768 >> 6, hd = n768 & 63;
    *(f16x8*)&dst[sbase + (long)s * 24576 + (long)head * 2048 + hd] = v;
  }
}

// ---------------------------------------------------------------------------
// K3: attention v2. 1 wave per (seq, head); all global reads dense 4KB blocks.
// V transposed through per-wave LDS (stride 66: both sides 2-way = free).
// O written token-major into Abuf for the output GEMM.
// ---------------------------------------------------------------------------
__global__ __launch_bounds__(256) void k_attn(const _Float16* __restrict__ Qp,
                                              const _Float16* __restrict__ Kp,
                                              const _Float16* __restrict__ Vp,
                                              const float* __restrict__ upen,
                                              _Float16* __restrict__ O) {
  __shared__ _Float16 lds[4][32 * 66 + 32 * 40];   // per-wave: Vs[32][66], Ps[32][40]
  const int w = threadIdx.x >> 6, lane = threadIdx.x & 63;
  const int seq = blockIdx.x / 3, hg = blockIdx.x % 3;
  const int head = hg * 4 + w;
  const int b = seq >> 8, s = seq & 255;
  _Float16* Vs = &lds[w][0];
  _Float16* Ps = &lds[w][32 * 66];
  const long base = (long)(seq * NHD + head) * 2048;
  const _Float16* Qb = Qp + base;
  const _Float16* Kb = Kp + base;
  const _Float16* Vb = Vp + base;

  // stage V (dense 4KB) -> LDS stride 66, f16x2 writes (2-way, free)
  {
    int t = lane & 31, hh = (lane >> 5) * 32;
    f16x8 vc[4];
    #pragma unroll
    for (int c = 0; c < 4; ++c) vc[c] = *(const f16x8*)(Vb + t * 64 + hh + c * 8);
    #pragma unroll
    for (int c = 0; c < 4; ++c)
      #pragma unroll
      for (int p = 0; p < 4; ++p) {
        union { _Float16 h[2]; unsigned u; } pk;
        pk.h[0] = vc[c][2 * p]; pk.h[1] = vc[c][2 * p + 1];
        *(unsigned*)&Vs[t * 66 + hh + c * 8 + 2 * p] = pk.u;
      }
  }
  // Q/K fragments direct from global (dense within the 4KB block)
  f16x8 qf[2][2], kf[2][2];
  #pragma unroll
  for (int i = 0; i < 2; ++i)
    #pragma unroll
    for (int ks = 0; ks < 2; ++ks) {
      int off = (i * 16 + (lane & 15)) * 64 + ks * 32 + (lane >> 4) * 8;
      qf[i][ks] = *(const f16x8*)(Qb + off);
      kf[i][ks] = *(const f16x8*)(Kb + off);
    }
  // scores = (Q/8) . K^T
  f32x4 sc[2][2] = {};
  #pragma unroll
  for (int mq = 0; mq < 2; ++mq)
    #pragma unroll
    for (int nk = 0; nk < 2; ++nk)
      #pragma unroll
      for (int ks = 0; ks < 2; ++ks)
        sc[mq][nk] = __builtin_amdgcn_mfma_f32_16x16x32_f16(qf[mq][ks], kf[nk][ks], sc[mq][nk], 0, 0, 0);

  const float up0 = upen[seq * TT + (lane & 15)];
  const float up1 = upen[seq * TT + 16 + (lane & 15)];

  // softmax over 32 keys per query row
  #pragma unroll
  for (int mq = 0; mq < 2; ++mq) {
    #pragma unroll
    for (int r = 0; r < 4; ++r) {
      float s0 = sc[mq][0][r] - up0;
      float s1 = sc[mq][1][r] - up1;
      float mx = fmaxf(s0, s1);
      #pragma unroll
      for (int off = 1; off < 16; off <<= 1) mx = fmaxf(mx, __shfl_xor(mx, off, 64));
      float e0 = __expf(s0 - mx), e1 = __expf(s1 - mx);
      float sum = e0 + e1;
      #pragma unroll
      for (int off = 1; off < 16; off <<= 1) sum += __shfl_xor(sum, off, 64);
      float inv = 1.0f / sum;
      int row = mq * 16 + (lane >> 4) * 4 + r;
      Ps[row * 40 + (lane & 15)]      = (_Float16)(e0 * inv);
      Ps[row * 40 + 16 + (lane & 15)] = (_Float16)(e1 * inv);
    }
  }
  // PV
  f16x8 pf[2];
  #pragma unroll
  for (int mq = 0; mq < 2; ++mq)
    pf[mq] = *(const f16x8*)(Ps + (mq * 16 + (lane & 15)) * 40 + (lane >> 4) * 8);
  f32x4 oacc[2][4] = {};
  #pragma unroll
  for (int nh = 0; nh < 4; ++nh) {
    int hd = nh * 16 + (lane & 15);
    f16x8 vf;
    #pragma unroll
    for (int j = 0; j < 8; ++j) vf[j] = Vs[((lane >> 4) * 8 + j) * 66 + hd];  // 2-way, free
    #pragma unroll
    for (int mq = 0; mq < 2; ++mq)
      oacc[mq][nh] = __builtin_amdgcn_mfma_f32_16x16x32_f16(pf[mq], vf, oacc[mq][nh], 0, 0, 0);
  }
  // write O token-major [m][768]
  #pragma unroll
  for (int mq = 0; mq < 2; ++mq)
    #pragma unroll
    for (int nh = 0; nh < 4; ++nh) {
      int hd = nh * 16 + (lane & 15);
      #pragma unroll
      for (int r = 0; r < 4; ++r) {
        int t = mq * 16 + (lane >> 4) * 4 + r;
        O[((long)((b << 5) + t) * SS + s) * DD + head * HD + hd] = (_Float16)oacc[mq][nh][r];
      }
    }
}

// ---------------------------------------------------------------------------
// K4: output GEMM, swapped operands: C'[R][token] = Wo[R][:] . O[token][:]
// Block tile 128R x 256tok, 4 waves of 64x128. ct-fastest for XCD locality.
// Writes final (B,T,D,Hp,Wp) fp32 with s-contiguous coalesced stores.
// ---------------------------------------------------------------------------
__global__ __launch_bounds__(256, 2) void k_gemm_out(const _Float16* __restrict__ Wn,
                                                     const _Float16* __restrict__ O,
                                                     const float* __restrict__ bo,
                                                     float* __restrict__ out) {
  __shared__ _Float16 As[128 * 32];   // Wo rows
  __shared__ _Float16 Bs[256 * 32];   // O token rows
  const int ct = blockIdx.x & 127, rt = blockIdx.x >> 7;   // ct-fastest
  const int R0 = rt * 128, C0 = ct * 256;
  const int tid = threadIdx.x, w = tid >> 6, lane = tid & 63;
  const int wr = (w >> 1) * 64, wcc = (w & 1) * 128;
  f32x4 acc[4][8] = {};
  for (int it = 0; it < 24; ++it) {
    const int k0 = it * 32;
    __syncthreads();
    #pragma unroll
    for (int i = 0; i < 2; ++i) {
      int c = tid + 256 * i;
      int row = c >> 2;
      int coff = ((c & 3) ^ (row & 3) ^ ((row >> 2) & 3)) * 8;
      _Float16* ldsA = (_Float16*)((char*)As + (w * 1024 + i * 4096 + lane * 16));
      async_copy16(Wn + (R0 + row) * DD + k0 + coff, ldsA);
    }
    #pragma unroll
    for (int i = 0; i < 4; ++i) {
      int c = tid + 256 * i;
      int row = c >> 2;
      int coff = ((c & 3) ^ (row & 3) ^ ((row >> 2) & 3)) * 8;
      _Float16* ldsB = (_Float16*)((char*)Bs + (w * 1024 + i * 4096 + lane * 16));
      async_copy16(O + (C0 + row) * DD + k0 + coff, ldsB);
    }
    __syncthreads();
    f16x8 af[4], bf[8];
    #pragma unroll
    for (int ri = 0; ri < 4; ++ri)
      af[ri] = *(const f16x8*)&As[swz_chunk(wr + ri * 16 + (lane & 15), lane >> 4) * 8];
    #pragma unroll
    for (int ci = 0; ci < 8; ++ci)
      bf[ci] = *(const f16x8*)&Bs[swz_chunk(wcc + ci * 16 + (lane & 15), lane >> 4) * 8];
    #pragma unroll
    for (int ri = 0; ri < 4; ++ri)
      #pragma unroll
      for (int ci = 0; ci < 8; ++ci)
        acc[ri][ci] = __builtin_amdgcn_mfma_f32_16x16x32_f16(af[ri], bf[ci], acc[ri][ci], 0, 0, 0);
  }
  const int slab = ct;                 // C-tile = all 256 tokens of one slab
  #pragma unroll
  for (int ri = 0; ri < 4; ++ri) {
    #pragma unroll
    for (int ci = 0; ci < 8; ++ci) {
      int s = wcc + ci * 16 + (lane & 15);
      f32x4 v = acc[ri][ci];
      #pragma unroll
      for (int r = 0; r < 4; ++r) {
        int R = R0 + wr + ri * 16 + (lane >> 4) * 4 + r;
        out[((long)slab * DD + R) * SS + s] = v[r] + bo[R];
      }
    }
  }
}

// ---------------------------------------------------------------------------
// host launcher.  ws layout (~197 MiB):
//   [0)          A f16 [32768][768]  (reused as O after attention)
//   [50331648)   WQKV f16 [2304][768]
//   [53870592)   Wo   f16 [768][768]
//   [55050240)   upen f32 [32768]
//   [55181312)   Qp f16 [1024][12][32][64]
//   [105512960)  Kp f16  (same shape)
//   [155844608)  Vp f16  (same shape)   end 206176256
// ---------------------------------------------------------------------------
extern "C" void kernel_launch(void* const* d_in, const int* in_sizes, int n_in,
                              void* d_out, int out_size, void* d_ws, size_t ws_size,
                              hipStream_t stream) {
  const float* h   = (const float*)d_in[0];
  const float* u   = (const float*)d_in[1];
  const float* lam = (const float*)d_in[2];
  const float* Wq  = (const float*)d_in[3];
  const float* bq  = (const float*)d_in[4];
  const float* Wk  = (const float*)d_in[5];
  const float* bk  = (const float*)d_in[6];
  const float* Wv  = (const float*)d_in[7];
  const float* bv  = (const float*)d_in[8];
  const float* Wo  = (const float*)d_in[9];
  const float* bo  = (const float*)d_in[10];
  float* out = (float*)d_out;

  char* ws = (char*)d_ws;
  _Float16* Abuf = (_Float16*)(ws);
  _Float16* WQKV = (_Float16*)(ws + 50331648);
  _Float16* WoH  = (_Float16*)(ws + 53870592);
  float*    upen = (float*)   (ws + 55050240);
  _Float16* Qp   = (_Float16*)(ws + 55181312);
  _Float16* Kp   = (_Float16*)(ws + 105512960);
  _Float16* Vp   = (_Float16*)(ws + 155844608);

  hipMemsetAsync(upen, 0, 32768 * sizeof(float), stream);
  k_transpose_h<<<dim3(128, 12), 256, 0, stream>>>(h, Abuf);
  k_convert_w<<<1152, 256, 0, stream>>>(Wq, Wk, Wv, Wo, WQKV, WoH);
  k_upen<<<512, 256, 0, stream>>>(u, lam, upen);
  k_gemm_qkv<<<1152, 512, 0, stream>>>(Abuf, WQKV, bq, bk, bv, Qp, Kp, Vp);
  k_attn<<<1024 * 3, 256, 0, stream>>>(Qp, Kp, Vp, upen, Abuf);
  k_gemm_out<<<128 * 6, 256, 0, stream>>>(WoH, Abuf, bo, out);
}

// Round 5
// 519.005 us; speedup vs baseline: 1.0313x; 1.0105x over previous
//
#include <hip/hip_runtime.h>

typedef float   f32x4 __attribute__((ext_vector_type(4)));
typedef _Float16 f16x8 __attribute__((ext_vector_type(8)));
typedef _Float16 f16x4 __attribute__((ext_vector_type(4)));

#define DEV static __device__ __forceinline__

// ---- problem constants ----
#define BB 4
#define TT 32
#define DD 768
#define SS 256          // Hp*Wp
#define NHD 12
#define HD 64
#define NSEQ  (BB*SS)   // 1024 sequences
#define MTOK  (NSEQ*TT) // 32768 tokens

DEV void async_copy16(const _Float16* g, _Float16* l) {
  __builtin_amdgcn_global_load_lds(
      (const __attribute__((address_space(1))) unsigned int*)g,
      (__attribute__((address_space(3))) unsigned int*)l,
      16, 0, 0);
}

// XOR-swizzled LDS 16B-chunk index for [rows][4 chunk] tiles (BK=32 f16).
DEV int swz_chunk(int r, int kc) {
  return r * 4 + (kc ^ (r & 3) ^ ((r >> 2) & 3));
}

// ---------------------------------------------------------------------------
// K0a: h (B,T,D,Hp,Wp) fp32 -> A[token][d] f16  (d<->s transpose via LDS)
// ---------------------------------------------------------------------------
__global__ __launch_bounds__(256) void k_transpose_h(const float* __restrict__ h,
                                                     _Float16* __restrict__ A) {
  __shared__ _Float16 Tl[256 * 65];
  const int slab = blockIdx.x;
  const int d0   = blockIdx.y * 64;
  const int t    = threadIdx.x;
  const float4* hv = (const float4*)(h + (slab * DD + d0) * SS);
  #pragma unroll
  for (int i = 0; i < 16; ++i) {
    int dd = i * 4 + (t >> 6);
    int s4 = (t & 63) * 4;
    float4 v = hv[dd * 64 + (t & 63)];
    Tl[(s4 + 0) * 65 + dd] = (_Float16)v.x;
    Tl[(s4 + 1) * 65 + dd] = (_Float16)v.y;
    Tl[(s4 + 2) * 65 + dd] = (_Float16)v.z;
    Tl[(s4 + 3) * 65 + dd] = (_Float16)v.w;
  }
  __syncthreads();
  #pragma unroll
  for (int p = 0; p < 8; ++p) {
    int s  = p * 32 + (t >> 3);
    int dd = (t & 7) * 8;
    f16x8 val;
    #pragma unroll
    for (int j = 0; j < 8; ++j) val[j] = Tl[s * 65 + dd + j];
    *(f16x8*)(A + (slab * SS + s) * DD + d0 + dd) = val;
  }
}

// ---------------------------------------------------------------------------
// K0b: weights fp32 -> f16
// ---------------------------------------------------------------------------
__global__ __launch_bounds__(256) void k_convert_w(const float* __restrict__ Wq,
                                                   const float* __restrict__ Wk,
                                                   const float* __restrict__ Wv,
                                                   const float* __restrict__ Wo,
                                                   _Float16* __restrict__ WQKV,
                                                   _Float16* __restrict__ WoH) {
  int idx = blockIdx.x * 256 + threadIdx.x;
  int row = idx / 96;
  int c8  = (idx % 96) * 8;
  const float* src; _Float16* dst;
  if (row < 768)       { src = Wq + row * 768;          dst = WQKV + row * 768; }
  else if (row < 1536) { src = Wk + (row - 768) * 768;  dst = WQKV + row * 768; }
  else if (row < 2304) { src = Wv + (row - 1536) * 768; dst = WQKV + row * 768; }
  else                 { src = Wo + (row - 2304) * 768; dst = WoH  + (row - 2304) * 768; }
  float4 v0 = *(const float4*)(src + c8);
  float4 v1 = *(const float4*)(src + c8 + 4);
  f16x8 o;
  o[0]=(_Float16)v0.x; o[1]=(_Float16)v0.y; o[2]=(_Float16)v0.z; o[3]=(_Float16)v0.w;
  o[4]=(_Float16)v1.x; o[5]=(_Float16)v1.y; o[6]=(_Float16)v1.z; o[7]=(_Float16)v1.w;
  *(f16x8*)(dst + c8) = o;
}

// ---------------------------------------------------------------------------
// K1: u_pen[(b*256+s)*32 + t] = lam * mean_d u
// ---------------------------------------------------------------------------
__global__ __launch_bounds__(256) void k_upen(const float* __restrict__ u,
                                              const float* __restrict__ lam,
                                              float* __restrict__ upen) {
  int slab = blockIdx.x >> 2;
  int q    = blockIdx.x & 3;
  int s    = threadIdx.x;
  const float* base = u + (slab * DD + q * 192) * SS + s;
  float sum = 0.f;
  for (int d = 0; d < 192; ++d) sum += base[d * SS];
  int b = slab >> 5, tt = slab & 31;
  float l = lam[slab * SS + s];
  atomicAdd(&upen[(b * SS + s) * TT + tt], sum * l * (1.0f / 768.0f));
}

// ---------------------------------------------------------------------------
// K2 v7: QKV GEMM, 256x256 tile, BK=32, 512 thr = 8 waves (2M x 4N).
// Ring-4 LDS + depth-3 prefetch + counted vmcnt(8) kept from v5/v6.
// REMOVED: per-phase lgkmcnt(0)/sched_barrier(0)/2nd barrier/setprio pins.
// Those serialized the LDS burst and MFMA burst across all 8 lockstep waves
// (LDS unit idle during MFMA, matrix pipe idle during ds_reads -> the flat
// ~165us/29% MfmaUtil of R2-R4).  New K-step:
//   { s_waitcnt vmcnt(8) ; s_barrier ; stage(t+3) ;
//     ds_reads + 32 MFMA, COMPILER-interleaved (fine lgkmcnt per fragment) }
// Hazards: barrier(t) orders all waves' reads-of-(t-1) (retired before their
// consuming MFMAs issued) BEFORE stage(t+3)'s overwrite of buf[(t-1)&3];
// per-wave vmcnt(8) before barrier publishes tile t to everyone.
// Swizzle v2: chunk slot = kc ^ (row&3) ^ ((row>>2)&1), both sides
// (stage source + ds_read) -> exactly 8 lanes per bank-quad = conflict-free
// (old (row&3)-only version had period-4 quad collisions = 4-way).
// Epilogue v2 (R4, verified): Ct staging + fully-coalesced f16x8 stores.
// ---------------------------------------------------------------------------
#define QSTEP(IT, VM, DO_STG)                                                  \
  {                                                                            \
    asm volatile("s_waitcnt " VM ::: "memory");                                \
    asm volatile("s_barrier" ::: "memory");                                    \
    if (DO_STG) {                                                              \
      const int kn_ = ((IT) + 3) * 32;                                         \
      stage(A, m0, &sh.g.As[((IT) + 3) & 3][0], kn_);                          \
      stage(Bw, n0, &sh.g.Bs[((IT) + 3) & 3][0], kn_);                         \
    }                                                                          \
    const int bt_ = (IT) & 3;                                                  \
    const _Float16* Ac = &sh.g.As[bt_][0];                                     \
    const _Float16* Bc = &sh.g.Bs[bt_][0];                                     \
    f16x8 af[8], bf[4];                                                        \
    _Pragma("unroll")                                                          \
    for (int mi = 0; mi < 8; ++mi) {                                           \
      int row = wm * 128 + mi * 16 + (lane & 15);                              \
      int kc = (lane >> 4) ^ (row & 3) ^ ((row >> 2) & 1);                     \
      af[mi] = *(const f16x8*)&Ac[(row * 4 + kc) * 8];                         \
    }                                                                          \
    _Pragma("unroll")                                                          \
    for (int ni = 0; ni < 4; ++ni) {                                           \
      int row = wn * 64 + ni * 16 + (lane & 15);                               \
      int kc = (lane >> 4) ^ (row & 3) ^ ((row >> 2) & 1);                     \
      bf[ni] = *(const f16x8*)&Bc[(row * 4 + kc) * 8];                         \
    }                                                                          \
    _Pragma("unroll")                                                          \
    for (int mi = 0; mi < 8; ++mi)                                             \
      _Pragma("unroll")                                                        \
      for (int ni = 0; ni < 4; ++ni)                                           \
        acc[mi][ni] = __builtin_amdgcn_mfma_f32_16x16x32_f16(bf[ni], af[mi],   \
                                                             acc[mi][ni], 0, 0, 0); \
  }

__global__ __launch_bounds__(512, 2) void k_gemm_qkv(const _Float16* __restrict__ A,
                                                     const _Float16* __restrict__ Bw,
                                                     const float* __restrict__ bq,
                                                     const float* __restrict__ bk,
                                                     const float* __restrict__ bv,
                                                     _Float16* __restrict__ Qp,
                                                     _Float16* __restrict__ Kp,
                                                     _Float16* __restrict__ Vp) {
  __shared__ __align__(16) union ShMem {
    struct { _Float16 As[4][256 * 32]; _Float16 Bs[4][256 * 32]; } g;  // 128KB
    _Float16 Ct[256 * 264];                                            // 135KB
  } sh;
  const int swz = (blockIdx.x & 7) * 144 + (blockIdx.x >> 3);   // 1152 = 8*144
  const int mt = swz / 9, nt = swz - mt * 9;
  const int m0 = mt * 256, n0 = nt * 256;
  const int tid = threadIdx.x, lane = tid & 63, w = tid >> 6;
  const int wm = w >> 2, wn = w & 3;       // wave rows wm*128.., cols wn*64..
  f32x4 acc[8][4] = {};

  // stage one matrix's 256x32 K-tile: 1024 16B-chunks, 2 per thread.
  // source pre-swizzled to match the read-side chunk slot (involution).
  auto stage = [&](const _Float16* __restrict__ g, int grow0, _Float16* l, int k0) {
    #pragma unroll
    for (int li = 0; li < 2; ++li) {
      int cc = tid + 512 * li;             // 16B chunk id, lane-linear dest
      int row = cc >> 2;                   // 4 chunks per 32-f16 row
      int kc = (cc & 3) ^ (row & 3) ^ ((row >> 2) & 1);
      async_copy16(g + (grow0 + row) * DD + k0 + kc * 8, l + cc * 8);
    }
  };

  // prologue: stage tiles 0,1,2 (12 loads/thread); loop steps do the waits.
  stage(A, m0, &sh.g.As[0][0], 0);  stage(Bw, n0, &sh.g.Bs[0][0], 0);
  stage(A, m0, &sh.g.As[1][0], 32); stage(Bw, n0, &sh.g.Bs[1][0], 32);
  stage(A, m0, &sh.g.As[2][0], 64); stage(Bw, n0, &sh.g.Bs[2][0], 64);

  for (int it = 0; it < 21; ++it) QSTEP(it, "vmcnt(8)", 1);
  QSTEP(21, "vmcnt(8)", 0);
  QSTEP(22, "vmcnt(4)", 0);
  QSTEP(23, "vmcnt(0)", 0);

  // ---- epilogue v2 ----
  // swapped-operand layout: s = wm*128 + mi*16 + (lane&15);
  //                         n = wn*64 + ni*16 + (lane>>4)*4 + r  (r consec!)
  const int sel = nt / 3;                                   // 0=Q 1=K 2=V
  const float scale = (sel == 0) ? 0.125f : 1.0f;           // fold 1/sqrt(64)
  const float* bias = (sel == 0) ? bq : ((sel == 1) ? bk : bv);
  _Float16* dst = (sel == 0) ? Qp : ((sel == 1) ? Kp : Vp);
  const int b = mt >> 5, t = mt & 31;
  const int nbias0 = nt * 256 - sel * 768;                  // sel-local col base

  __syncthreads();   // all waves done reading ring bufs before Ct overlay
  #pragma unroll
  for (int ni = 0; ni < 4; ++ni) {
    int n_l = wn * 64 + ni * 16 + (lane >> 4) * 4;          // 4-aligned
    float4 bsv = *(const float4*)&bias[nbias0 + n_l];
    #pragma unroll
    for (int mi = 0; mi < 8; ++mi) {
      int s = wm * 128 + mi * 16 + (lane & 15);
      f32x4 v = acc[mi][ni];
      f16x4 pk;
      pk[0] = (_Float16)((v[0] + bsv.x) * scale);
      pk[1] = (_Float16)((v[1] + bsv.y) * scale);
      pk[2] = (_Float16)((v[2] + bsv.z) * scale);
      pk[3] = (_Float16)((v[3] + bsv.w) * scale);
      *(f16x4*)&sh.Ct[s * 264 + n_l] = pk;
    }
  }
  __syncthreads();
  // coalesced stores: thread -> (s, n-octet); 8 lanes = 128B contiguous run.
  const long sbase = ((long)b * 256) * 24576 + (long)t * 64;
  #pragma unroll
  for (int rep = 0; rep < 16; ++rep) {
    int id = rep * 512 + tid;           // 8192 octets = 256s x 32
    int s = id >> 5, c8 = id & 31;
    int n = c8 * 8;
    f16x8 v = *(const f16x8*)&sh.Ct[s * 264 + n];
    int n768 = nbias0 + n;
    int head = n768 >> 6, hd = n768 & 63;
    *(f16x8*)&dst[sbase + (long)s * 24576 + (long)head * 2048 + hd] = v;
  }
}

// ---------------------------------------------------------------------------
// K3: attention v2. 1 wave per (seq, head); all global reads dense 4KB blocks.
// V transposed through per-wave LDS (stride 66: both sides 2-way = free).
// O written token-major into Abuf for the output GEMM.
// ---------------------------------------------------------------------------
__global__ __launch_bounds__(256) void k_attn(const _Float16* __restrict__ Qp,
                                              const _Float16* __restrict__ Kp,
                                              const _Float16* __restrict__ Vp,
                                              const float* __restrict__ upen,
                                              _Float16* __restrict__ O) {
  __shared__ _Float16 lds[4][32 * 66 + 32 * 40];   // per-wave: Vs[32][66], Ps[32][40]
  const int w = threadIdx.x >> 6, lane = threadIdx.x & 63;
  const int seq = blockIdx.x / 3, hg = blockIdx.x % 3;
  const int head = hg * 4 + w;
  const int b = seq >> 8, s = seq & 255;
  _Float16* Vs = &lds[w][0];
  _Float16* Ps = &lds[w][32 * 66];
  const long base = (long)(seq * NHD + head) * 2048;
  const _Float16* Qb = Qp + base;
  const _Float16* Kb = Kp + base;
  const _Float16* Vb = Vp + base;

  // stage V (dense 4KB) -> LDS stride 66, f16x2 writes (2-way, free)
  {
    int t = lane & 31, hh = (lane >> 5) * 32;
    f16x8 vc[4];
    #pragma unroll
    for (int c = 0; c < 4; ++c) vc[c] = *(const f16x8*)(Vb + t * 64 + hh + c * 8);
    #pragma unroll
    for (int c = 0; c < 4; ++c)
      #pragma unroll
      for (int p = 0; p < 4; ++p) {
        union { _Float16 h[2]; unsigned u; } pk;
        pk.h[0] = vc[c][2 * p]; pk.h[1] = vc[c][2 * p + 1];
        *(unsigned*)&Vs[t * 66 + hh + c * 8 + 2 * p] = pk.u;
      }
  }
  // Q/K fragments direct from global (dense within the 4KB block)
  f16x8 qf[2][2], kf[2][2];
  #pragma unroll
  for (int i = 0; i < 2; ++i)
    #pragma unroll
    for (int ks = 0; ks < 2; ++ks) {
      int off = (i * 16 + (lane & 15)) * 64 + ks * 32 + (lane >> 4) * 8;
      qf[i][ks] = *(const f16x8*)(Qb + off);
      kf[i][ks] = *(const f16x8*)(Kb + off);
    }
  // scores = (Q/8) . K^T
  f32x4 sc[2][2] = {};
  #pragma unroll
  for (int mq = 0; mq < 2; ++mq)
    #pragma unroll
    for (int nk = 0; nk < 2; ++nk)
      #pragma unroll
      for (int ks = 0; ks < 2; ++ks)
        sc[mq][nk] = __builtin_amdgcn_mfma_f32_16x16x32_f16(qf[mq][ks], kf[nk][ks], sc[mq][nk], 0, 0, 0);

  const float up0 = upen[seq * TT + (lane & 15)];
  const float up1 = upen[seq * TT + 16 + (lane & 15)];

  // softmax over 32 keys per query row
  #pragma unroll
  for (int mq = 0; mq < 2; ++mq) {
    #pragma unroll
    for (int r = 0; r < 4; ++r) {
      float s0 = sc[mq][0][r] - up0;
      float s1 = sc[mq][1][r] - up1;
      float mx = fmaxf(s0, s1);
      #pragma unroll
      for (int off = 1; off < 16; off <<= 1) mx = fmaxf(mx, __shfl_xor(mx, off, 64));
      float e0 = __expf(s0 - mx), e1 = __expf(s1 - mx);
      float sum = e0 + e1;
      #pragma unroll
      for (int off = 1; off < 16; off <<= 1) sum += __shfl_xor(sum, off, 64);
      float inv = 1.0f / sum;
      int row = mq * 16 + (lane >> 4) * 4 + r;
      Ps[row * 40 + (lane & 15)]      = (_Float16)(e0 * inv);
      Ps[row * 40 + 16 + (lane & 15)] = (_Float16)(e1 * inv);
    }
  }
  // PV
  f16x8 pf[2];
  #pragma unroll
  for (int mq = 0; mq < 2; ++mq)
    pf[mq] = *(const f16x8*)(Ps + (mq * 16 + (lane & 15)) * 40 + (lane >> 4) * 8);
  f32x4 oacc[2][4] = {};
  #pragma unroll
  for (int nh = 0; nh < 4; ++nh) {
    int hd = nh * 16 + (lane & 15);
    f16x8 vf;
    #pragma unroll
    for (int j = 0; j < 8; ++j) vf[j] = Vs[((lane >> 4) * 8 + j) * 66 + hd];  // 2-way, free
    #pragma unroll
    for (int mq = 0; mq < 2; ++mq)
      oacc[mq][nh] = __builtin_amdgcn_mfma_f32_16x16x32_f16(pf[mq], vf, oacc[mq][nh], 0, 0, 0);
  }
  // write O token-major [m][768]
  #pragma unroll
  for (int mq = 0; mq < 2; ++mq)
    #pragma unroll
    for (int nh = 0; nh < 4; ++nh) {
      int hd = nh * 16 + (lane & 15);
      #pragma unroll
      for (int r = 0; r < 4; ++r) {
        int t = mq * 16 + (lane >> 4) * 4 + r;
        O[((long)((b << 5) + t) * SS + s) * DD + head * HD + hd] = (_Float16)oacc[mq][nh][r];
      }
    }
}

// ---------------------------------------------------------------------------
// K4: output GEMM, swapped operands: C'[R][token] = Wo[R][:] . O[token][:]
// Block tile 128R x 256tok, 4 waves of 64x128. ct-fastest for XCD locality.
// Writes final (B,T,D,Hp,Wp) fp32 with s-contiguous coalesced stores.
// ---------------------------------------------------------------------------
__global__ __launch_bounds__(256, 2) void k_gemm_out(const _Float16* __restrict__ Wn,
                                                     const _Float16* __restrict__ O,
                                                     const float* __restrict__ bo,
                                                     float* __restrict__ out) {
  __shared__ _Float16 As[128 * 32];   // Wo rows
  __shared__ _Float16 Bs[256 * 32];   // O token rows
  const int ct = blockIdx.x & 127, rt = blockIdx.x >> 7;   // ct-fastest
  const int R0 = rt * 128, C0 = ct * 256;
  const int tid = threadIdx.x, w = tid >> 6, lane = tid & 63;
  const int wr = (w >> 1) * 64, wcc = (w & 1) * 128;
  f32x4 acc[4][8] = {};
  for (int it = 0; it < 24; ++it) {
    const int k0 = it * 32;
    __syncthreads();
    #pragma unroll
    for (int i = 0; i < 2; ++i) {
      int c = tid + 256 * i;
      int row = c >> 2;
      int coff = ((c & 3) ^ (row & 3) ^ ((row >> 2) & 3)) * 8;
      _Float16* ldsA = (_Float16*)((char*)As + (w * 1024 + i * 4096 + lane * 16));
      async_copy16(Wn + (R0 + row) * DD + k0 + coff, ldsA);
    }
    #pragma unroll
    for (int i = 0; i < 4; ++i) {
      int c = tid + 256 * i;
      int row = c >> 2;
      int coff = ((c & 3) ^ (row & 3) ^ ((row >> 2) & 3)) * 8;
      _Float16* ldsB = (_Float16*)((char*)Bs + (w * 1024 + i * 4096 + lane * 16));
      async_copy16(O + (C0 + row) * DD + k0 + coff, ldsB);
    }
    __syncthreads();
    f16x8 af[4], bf[8];
    #pragma unroll
    for (int ri = 0; ri < 4; ++ri)
      af[ri] = *(const f16x8*)&As[swz_chunk(wr + ri * 16 + (lane & 15), lane >> 4) * 8];
    #pragma unroll
    for (int ci = 0; ci < 8; ++ci)
      bf[ci] = *(const f16x8*)&Bs[swz_chunk(wcc + ci * 16 + (lane & 15), lane >> 4) * 8];
    #pragma unroll
    for (int ri = 0; ri < 4; ++ri)
      #pragma unroll
      for (int ci = 0; ci < 8; ++ci)
        acc[ri][ci] = __builtin_amdgcn_mfma_f32_16x16x32_f16(af[ri], bf[ci], acc[ri][ci], 0, 0, 0);
  }
  const int slab = ct;                 // C-tile = all 256 tokens of one slab
  #pragma unroll
  for (int ri = 0; ri < 4; ++ri) {
    #pragma unroll
    for (int ci = 0; ci < 8; ++ci) {
      int s = wcc + ci * 16 + (lane & 15);
      f32x4 v = acc[ri][ci];
      #pragma unroll
      for (int r = 0; r < 4; ++r) {
        int R = R0 + wr + ri * 16 + (lane >> 4) * 4 + r;
        out[((long)slab * DD + R) * SS + s] = v[r] + bo[R];
      }
    }
  }
}

// ---------------------------------------------------------------------------
// host launcher.  ws layout (~197 MiB):
//   [0)          A f16 [32768][768]  (reused as O after attention)
//   [50331648)   WQKV f16 [2304][768]
//   [53870592)   Wo   f16 [768][768]
//   [55050240)   upen f32 [32768]
//   [55181312)   Qp f16 [1024][12][32][64]
//   [105512960)  Kp f16  (same shape)
//   [155844608)  Vp f16  (same shape)   end 206176256
// ---------------------------------------------------------------------------
extern "C" void kernel_launch(void* const* d_in, const int* in_sizes, int n_in,
                              void* d_out, int out_size, void* d_ws, size_t ws_size,
                              hipStream_t stream) {
  const float* h   = (const float*)d_in[0];
  const float* u   = (const float*)d_in[1];
  const float* lam = (const float*)d_in[2];
  const float* Wq  = (const float*)d_in[3];
  const float* bq  = (const float*)d_in[4];
  const float* Wk  = (const float*)d_in[5];
  const float* bk  = (const float*)d_in[6];
  const float* Wv  = (const float*)d_in[7];
  const float* bv  = (const float*)d_in[8];
  const float* Wo  = (const float*)d_in[9];
  const float* bo  = (const float*)d_in[10];
  float* out = (float*)d_out;

  char* ws = (char*)d_ws;
  _Float16* Abuf = (_Float16*)(ws);
  _Float16* WQKV = (_Float16*)(ws + 50331648);
  _Float16* WoH  = (_Float16*)(ws + 53870592);
  float*    upen = (float*)   (ws + 55050240);
  _Float16* Qp   = (_Float16*)(ws + 55181312);
  _Float16* Kp   = (_Float16*)(ws + 105512960);
  _Float16* Vp   = (_Float16*)(ws + 155844608);

  hipMemsetAsync(upen, 0, 32768 * sizeof(float), stream);
  k_transpose_h<<<dim3(128, 12), 256, 0, stream>>>(h, Abuf);
  k_convert_w<<<1152, 256, 0, stream>>>(Wq, Wk, Wv, Wo, WQKV, WoH);
  k_upen<<<512, 256, 0, stream>>>(u, lam, upen);
  k_gemm_qkv<<<1152, 512, 0, stream>>>(Abuf, WQKV, bq, bk, bv, Qp, Kp, Vp);
  k_attn<<<1024 * 3, 256, 0, stream>>>(Qp, Kp, Vp, upen, Abuf);
  k_gemm_out<<<128 * 6, 256, 0, stream>>>(WoH, Abuf, bo, out);
}